// Round 6
// baseline (146.559 us; speedup 1.0000x reference)
//
#include <hip/hip_runtime.h>

#define NCTX 2048
#define NH   8
#define WD   32
#define NTOK 512

static constexpr float SCALE = 0.04419417382415922f; // 1/sqrt(512)

// Block = 512 thr (8 waves) = one (plane, 64-row group, j-window of 512/S).
// lane = row (kg[32], acc[32] in VGPRs, <=64 VGPR -> 8 waves/SIMD).
// q/v rows of the j-window staged in LDS; bodies read wave-uniform rows via
// ds_read broadcast. S-way j-split combined via ws + combine kernel.
// S=8: grid 1024 = 4 blocks/CU = 32 waves/CU (full occupancy) -> TLP hides
// the per-body LDS latency that ILP attempts (R1-R4) failed to hide.
template<int S>
__global__ __launch_bounds__(512, 8) void l1attn_main(
    const float* __restrict__ q, const float* __restrict__ k,
    const float* __restrict__ v, const int* __restrict__ indx,
    float* __restrict__ dst /* S>1 ? ws : out */) {
  constexpr int WIN = NTOK / S;          // tokens per j-window
  __shared__ int   indxS[NTOK];
  __shared__ float ldsQ[WIN * 32];
  __shared__ float ldsV[WIN * 32];
  __shared__ float accS[64 * 33];        // [row][w] stride 33
  __shared__ float lS[64];

  const int tid  = threadIdx.x;
  const int bid  = blockIdx.x;
  const int pr   = bid / S;              // plane*8 + rowgroup   [0,128)
  const int jw   = bid % S;              // j-window
  const int b    = pr >> 6;
  const int h    = (pr >> 3) & 7;
  const int rg   = pr & 7;

  // phase 1: indx + zero accumulators
  indxS[tid] = indx[tid];
  for (int i = tid; i < 64 * 33; i += 512) accS[i] = 0.f;
  if (tid < 64) lS[tid] = 0.f;
  __syncthreads();

  const float* qb = q + ((size_t)b * NCTX * NH) * WD + h * WD;
  const float* vb = v + ((size_t)b * NCTX * NH) * WD + h * WD;
  const float* kb = k + ((size_t)b * NCTX * NH) * WD + h * WD;

  // phase 2: stage q/v rows of this j-window into LDS (gather via indx)
  for (int i = tid; i < WIN * 8; i += 512) {
    const int t = i >> 3, sg = i & 7;    // token-in-window, float4 segment
    const int tok = indxS[jw * WIN + t];
    const float4* qr = (const float4*)(qb + (size_t)tok * (NH * WD));
    const float4* vr = (const float4*)(vb + (size_t)tok * (NH * WD));
    ((float4*)ldsQ)[i] = qr[sg];
    ((float4*)ldsV)[i] = vr[sg];
  }

  // per-lane K row (output row s keys on k per the einsum relabeling)
  const int lane = tid & 63;
  const int wave = __builtin_amdgcn_readfirstlane(tid >> 6);  // 0..7
  float kg[32];
  {
    const int s = rg * 64 + lane;
    const float4* kr = (const float4*)(kb + (size_t)indxS[s] * (NH * WD));
#pragma unroll
    for (int i = 0; i < 8; ++i) {
      float4 t = kr[i];
      kg[4*i+0] = t.x; kg[4*i+1] = t.y; kg[4*i+2] = t.z; kg[4*i+3] = t.w;
    }
  }

  float acc[32];
#pragma unroll
  for (int i = 0; i < 32; ++i) acc[i] = 0.f;
  float l = 0.f;

  __syncthreads();

  // phase 3: bodies — wave handles WIN/8 j's, rows = lanes
  constexpr int JPW = WIN / 8;
  const int jloc0 = wave * JPW;
  for (int jj = 0; jj < JPW; ++jj) {
    const float* qrow = ldsQ + (jloc0 + jj) * 32;   // wave-uniform -> broadcast
    const float* vrow = ldsV + (jloc0 + jj) * 32;

    float d0, d1, d2, d3;
    {
      float4 t = ((const float4*)qrow)[0];
      d0 = fabsf(t.x - kg[0]); d1 = fabsf(t.y - kg[1]);
      d2 = fabsf(t.z - kg[2]); d3 = fabsf(t.w - kg[3]);
    }
#pragma unroll
    for (int i = 1; i < 8; ++i) {
      float4 t = ((const float4*)qrow)[i];
      d0 += fabsf(t.x - kg[4*i+0]);
      d1 += fabsf(t.y - kg[4*i+1]);
      d2 += fabsf(t.z - kg[4*i+2]);
      d3 += fabsf(t.w - kg[4*i+3]);
    }
    const float d = (d0 + d1) + (d2 + d3);
    const float p = __expf(-SCALE * d);  // d in [0,~350]: no max-shift needed
    l += p;
#pragma unroll
    for (int i = 0; i < 8; ++i) {
      float4 t = ((const float4*)vrow)[i];
      acc[4*i+0] = fmaf(p, t.x, acc[4*i+0]);
      acc[4*i+1] = fmaf(p, t.y, acc[4*i+1]);
      acc[4*i+2] = fmaf(p, t.z, acc[4*i+2]);
      acc[4*i+3] = fmaf(p, t.w, acc[4*i+3]);
    }
  }

  // phase 4: combine the 8 wave partials (same 64 rows) in LDS
#pragma unroll
  for (int w = 0; w < 32; ++w) atomicAdd(&accS[lane * 33 + w], acc[w]);
  atomicAdd(&lS[lane], l);
  __syncthreads();

  // phase 5: write out / partial
  if (S > 1) {
    float* wsB = dst + (size_t)bid * 2112;          // 64*32 acc + 64 l
    for (int i = tid; i < 2048; i += 512)
      wsB[i] = accS[(i >> 5) * 33 + (i & 31)];
    if (tid < 64) wsB[2048 + tid] = lS[tid];
  } else {
    for (int i = tid; i < 2048; i += 512) {
      const int r = i >> 5, w = i & 31;
      dst[(((size_t)b * NTOK + rg * 64 + r) * NH + h) * WD + w] =
          accS[r * 33 + w] / lS[r];
    }
  }
}

template<int S>
__global__ __launch_bounds__(1024) void l1attn_combine(
    const float* __restrict__ ws, float* __restrict__ out) {
  const int gid = blockIdx.x * 1024 + threadIdx.x;  // [0, 262144)
  const int w  = gid & 31;
  const int r  = (gid >> 5) & 63;
  const int pr = gid >> 11;                         // [0, 128)
  const float* base = ws + (size_t)pr * S * 2112;
  float a = 0.f, ls = 0.f;
#pragma unroll
  for (int jwi = 0; jwi < S; ++jwi) {
    a  += base[jwi * 2112 + r * 32 + w];
    ls += base[jwi * 2112 + 2048 + r];
  }
  const int b = pr >> 6, h = (pr >> 3) & 7, rg = pr & 7;
  out[(((size_t)b * NTOK + rg * 64 + r) * NH + h) * WD + w] = a / ls;
}

extern "C" void kernel_launch(void* const* d_in, const int* in_sizes, int n_in,
                              void* d_out, int out_size, void* d_ws, size_t ws_size,
                              hipStream_t stream) {
  const float* q    = (const float*)d_in[0];
  const float* k    = (const float*)d_in[1];
  const float* v    = (const float*)d_in[2];
  const int*   indx = (const int*)d_in[3];
  float*       out  = (float*)d_out;

  const size_t need8 = (size_t)1024 * 2112 * sizeof(float);  // 8.7 MB
  const size_t need4 = (size_t)512  * 2112 * sizeof(float);  // 4.3 MB
  const size_t need2 = (size_t)256  * 2112 * sizeof(float);  // 2.2 MB
  if (ws_size >= need8) {
    hipLaunchKernelGGL((l1attn_main<8>), dim3(1024), dim3(512), 0, stream,
                       q, k, v, indx, (float*)d_ws);
    hipLaunchKernelGGL((l1attn_combine<8>), dim3(256), dim3(1024), 0, stream,
                       (const float*)d_ws, out);
  } else if (ws_size >= need4) {
    hipLaunchKernelGGL((l1attn_main<4>), dim3(512), dim3(512), 0, stream,
                       q, k, v, indx, (float*)d_ws);
    hipLaunchKernelGGL((l1attn_combine<4>), dim3(256), dim3(1024), 0, stream,
                       (const float*)d_ws, out);
  } else if (ws_size >= need2) {
    hipLaunchKernelGGL((l1attn_main<2>), dim3(256), dim3(512), 0, stream,
                       q, k, v, indx, (float*)d_ws);
    hipLaunchKernelGGL((l1attn_combine<2>), dim3(256), dim3(1024), 0, stream,
                       (const float*)d_ws, out);
  } else {
    hipLaunchKernelGGL((l1attn_main<1>), dim3(128), dim3(512), 0, stream,
                       q, k, v, indx, out);
  }
}

// Round 7
// 64.956 us; speedup vs baseline: 2.2563x; 2.2563x over previous
//
#include <hip/hip_runtime.h>

#define NCTX 2048
#define NH   8
#define WD   32
#define NTOK 512

static constexpr float SCALE = 0.04419417382415922f; // 1/sqrt(512)

// Block = 512 thr (8 waves) = one (plane, 32-row group, j-span of 512/S).
// lane = whalf*32 + r: each lane owns HALF a row (kg[16], acc[16]) so live
// state ~52 VGPRs -> 6 waves/SIMD without spilling (R6 post-mortem: a 64-reg
// cap with 80 live spilled acc to scratch -> 200 MB scratch traffic).
// j-span staged into LDS in 128-token windows; bodies read wave-uniform rows
// via broadcast ds_read_b128. d combined across the two half-lanes with one
// __shfl_xor. S-way j-split combined via ws + combine kernel.
template<int S>
__global__ __launch_bounds__(512, 6) void l1attn_main(
    const float* __restrict__ q, const float* __restrict__ k,
    const float* __restrict__ v, const int* __restrict__ indx,
    float* __restrict__ dst /* S>1 ? ws : out */) {
  constexpr int JSPAN = NTOK / S;       // tokens this block accumulates
  constexpr int NWIN  = JSPAN / 128;    // staged 128 tokens at a time
  __shared__ int   indxS[NTOK];
  __shared__ float ldsQ[128 * 32];
  __shared__ float ldsV[128 * 32];
  __shared__ float accS[32 * 33];       // [row][w] stride 33
  __shared__ float lS[32];

  const int tid = threadIdx.x;
  const int bid = blockIdx.x;
  const int pr  = bid / S;              // plane*16 + rowgroup   [0,256)
  const int jw  = bid % S;              // j-span index
  const int plane = pr >> 4;            // b*8 + h
  const int rg    = pr & 15;
  const int b     = plane >> 3;
  const int h     = plane & 7;

  // phase 1: indx + zero accumulators
  indxS[tid] = indx[tid];
  for (int i = tid; i < 32 * 33; i += 512) accS[i] = 0.f;
  if (tid < 32) lS[tid] = 0.f;
  __syncthreads();

  const float* qb = q + ((size_t)b * NCTX * NH) * WD + h * WD;
  const float* vb = v + ((size_t)b * NCTX * NH) * WD + h * WD;
  const float* kb = k + ((size_t)b * NCTX * NH) * WD + h * WD;

  const int lane  = tid & 63;
  const int wave  = __builtin_amdgcn_readfirstlane(tid >> 6); // 0..7
  const int r     = lane & 31;          // row within group
  const int whalf = lane >> 5;          // which 16 of the 32 w's

  // per-lane half K-row (output row s keys on k per the einsum relabeling)
  float kg[16];
  {
    const int s = rg * 32 + r;
    const float4* kr =
        (const float4*)(kb + (size_t)indxS[s] * (NH * WD) + whalf * 16);
#pragma unroll
    for (int i = 0; i < 4; ++i) {
      float4 t = kr[i];
      kg[4*i+0] = t.x; kg[4*i+1] = t.y; kg[4*i+2] = t.z; kg[4*i+3] = t.w;
    }
  }

  float acc[16];
#pragma unroll
  for (int i = 0; i < 16; ++i) acc[i] = 0.f;
  float l = 0.f;

  for (int wnd = 0; wnd < NWIN; ++wnd) {
    if (wnd) __syncthreads();           // previous window fully consumed

    // stage 128 tokens' q/v rows into LDS (gather via indx), coalesced 128B
    const int tok0 = jw * JSPAN + wnd * 128;
    for (int i = tid; i < 128 * 8; i += 512) {
      const int t = i >> 3, sg = i & 7; // token-in-window, float4 segment
      const int tok = indxS[tok0 + t];
      ((float4*)ldsQ)[i] = ((const float4*)(qb + (size_t)tok * (NH * WD)))[sg];
      ((float4*)ldsV)[i] = ((const float4*)(vb + (size_t)tok * (NH * WD)))[sg];
    }
    __syncthreads();

    // bodies: this wave's 16 j's of the window; rows = lanes (mod 32)
    const int j0 = wave * 16;
    for (int jj = 0; jj < 16; ++jj) {
      const float* qrow = ldsQ + (j0 + jj) * 32 + whalf * 16; // half-broadcast
      const float* vrow = ldsV + (j0 + jj) * 32 + whalf * 16;

      float d0, d1, d2, d3;
      {
        float4 t = ((const float4*)qrow)[0];
        d0 = fabsf(t.x - kg[0]); d1 = fabsf(t.y - kg[1]);
        d2 = fabsf(t.z - kg[2]); d3 = fabsf(t.w - kg[3]);
      }
#pragma unroll
      for (int i = 1; i < 4; ++i) {
        float4 t = ((const float4*)qrow)[i];
        d0 += fabsf(t.x - kg[4*i+0]);
        d1 += fabsf(t.y - kg[4*i+1]);
        d2 += fabsf(t.z - kg[4*i+2]);
        d3 += fabsf(t.w - kg[4*i+3]);
      }
      float d = (d0 + d1) + (d2 + d3);
      d += __shfl_xor(d, 32, 64);       // combine the two half-rows
      const float p = __expf(-SCALE * d); // d in [0,~350]: no max-shift needed
      l += p;
#pragma unroll
      for (int i = 0; i < 4; ++i) {
        float4 t = ((const float4*)vrow)[i];
        acc[4*i+0] = fmaf(p, t.x, acc[4*i+0]);
        acc[4*i+1] = fmaf(p, t.y, acc[4*i+1]);
        acc[4*i+2] = fmaf(p, t.z, acc[4*i+2]);
        acc[4*i+3] = fmaf(p, t.w, acc[4*i+3]);
      }
    }
  }

  // combine the 8 wave partials (same 32 rows) in LDS
#pragma unroll
  for (int w = 0; w < 16; ++w)
    atomicAdd(&accS[r * 33 + whalf * 16 + w], acc[w]);
  if (whalf == 0) atomicAdd(&lS[r], l);
  __syncthreads();

  // write out / partial
  if (S > 1) {
    float* wsB = dst + (size_t)bid * 1056;          // 32*32 acc + 32 l
    for (int i = tid; i < 1024; i += 512)
      wsB[i] = accS[(i >> 5) * 33 + (i & 31)];
    if (tid < 32) wsB[1024 + tid] = lS[tid];
  } else {
    for (int i = tid; i < 1024; i += 512) {
      const int rr = i >> 5, w = i & 31;
      dst[(((size_t)b * NTOK + rg * 32 + rr) * NH + h) * WD + w] =
          accS[rr * 33 + w] / lS[rr];
    }
  }
}

template<int S>
__global__ __launch_bounds__(1024) void l1attn_combine(
    const float* __restrict__ ws, float* __restrict__ out) {
  const int gid = blockIdx.x * 1024 + threadIdx.x;  // [0, 262144)
  const int w  = gid & 31;
  const int r  = (gid >> 5) & 31;
  const int pr = gid >> 10;                         // [0, 256)
  const float* base = ws + (size_t)pr * S * 1056;
  float a = 0.f, ls = 0.f;
#pragma unroll
  for (int jwi = 0; jwi < S; ++jwi) {
    a  += base[jwi * 1056 + r * 32 + w];
    ls += base[jwi * 1056 + 1024 + r];
  }
  const int plane = pr >> 4, rg = pr & 15;
  const int b = plane >> 3, h = plane & 7;
  out[(((size_t)b * NTOK + rg * 32 + r) * NH + h) * WD + w] = a / ls;
}

extern "C" void kernel_launch(void* const* d_in, const int* in_sizes, int n_in,
                              void* d_out, int out_size, void* d_ws, size_t ws_size,
                              hipStream_t stream) {
  const float* q    = (const float*)d_in[0];
  const float* k    = (const float*)d_in[1];
  const float* v    = (const float*)d_in[2];
  const int*   indx = (const int*)d_in[3];
  float*       out  = (float*)d_out;

  const size_t need4 = (size_t)1024 * 1056 * sizeof(float);  // 4.3 MB
  const size_t need2 = (size_t)512  * 1056 * sizeof(float);  // 2.2 MB
  if (ws_size >= need4) {
    hipLaunchKernelGGL((l1attn_main<4>), dim3(1024), dim3(512), 0, stream,
                       q, k, v, indx, (float*)d_ws);
    hipLaunchKernelGGL((l1attn_combine<4>), dim3(256), dim3(1024), 0, stream,
                       (const float*)d_ws, out);
  } else if (ws_size >= need2) {
    hipLaunchKernelGGL((l1attn_main<2>), dim3(512), dim3(512), 0, stream,
                       q, k, v, indx, (float*)d_ws);
    hipLaunchKernelGGL((l1attn_combine<2>), dim3(256), dim3(1024), 0, stream,
                       (const float*)d_ws, out);
  } else {
    hipLaunchKernelGGL((l1attn_main<1>), dim3(256), dim3(512), 0, stream,
                       q, k, v, indx, out);
  }
}